// Round 15
// baseline (140.444 us; speedup 1.0000x reference)
//
#include <hip/hip_runtime.h>

// SimVQuantizer: B=8, D=128 (N_CB=8 x CDIM=16), H=W=32 -> 8192 pixels.
// Outputs (FLOAT32, concatenated flat):
//   quantized  [8,128,32,32]  = 1048576   @ 0
//   indices    [8,8,32,32]    =   65536   @ 1048576
//   commitment scalar         =       1   @ 1114112
//   new_codebooks [8,1024,16] =  131072   @ 1114113
//   new_count  [8,1024]       =    8192   @ 1245185
//   new_weight [8,1024,16]    =  131072   @ 1253377

#define NCB   8
#define VOCAB 1024
#define CDIM  16
#define NPIX  8192   // B*H*W
#define HW    1024   // H*W

#define OFF_QUANT  0
#define OFF_IDX    1048576
#define OFF_COMMIT 1114112
#define OFF_NCB    1114113
#define OFF_NCNT   1245185
#define OFF_NWT    1253377

// workspace layout (floats):
//   counts_p [8][2][1024]      @ 0       (per-(c,half) partial counts)
//   sums_p   [8][16][2][1024]  @ 16384   (per-(c,d,half) partial sums)
//   commit_arr [256]           @ 278528  (per-assign-block partials)
// No memset: every word is written before it is read.
// Lessons pinned: no global atomics in hot paths (v6); no per-block
// __threadfence finisher patterns (v10); SMEM s_loads can't be counted-
// pipelined (out-of-order -> lgkmcnt(0) only); packed-f32 never reduces
// issue count on hipcc (v9, v12); 3-kernel split is structurally optimal
// (fusions v7/v10/v14 all regressed); R-blocking is safe ONLY with
// SGPR-resident entries (VGPR entry staging spilled in v2/v3).
#define WS_CNTP_OFF 0
#define WS_SUMP_OFF (NCB * 2 * VOCAB)
#define WS_CARR_OFF (NCB * 2 * VOCAB + NCB * CDIM * 2 * VOCAB)

// numpy pairwise_sum (order-preserving 8-accumulator) for n=16:
// r[j] = a[j] + a[j+8];  res = ((r0+r1)+(r2+r3)) + ((r4+r5)+(r6+r7))
__device__ __forceinline__ float npsum16(const float m[16]) {
#pragma clang fp contract(off)
  float r0 = m[0] + m[8];
  float r1 = m[1] + m[9];
  float r2 = m[2] + m[10];
  float r3 = m[3] + m[11];
  float r4 = m[4] + m[12];
  float r5 = m[5] + m[13];
  float r6 = m[6] + m[14];
  float r7 = m[7] + m[15];
  return ((r0 + r1) + (r2 + r3)) + ((r4 + r5) + (r6 + r7));
}

__device__ __forceinline__ float npsum16sq(const float a[16]) {
#pragma clang fp contract(off)
  float m[16];
#pragma unroll
  for (int d = 0; d < 16; ++d) m[d] = a[d] * a[d];
  return npsum16(m);
}

// One entry's distance + argmin step. numpy einsum (optimize=False) npyv
// contig order for n=16, then (z2 - 2*dot) + c2 — bit-identical to v1.
__device__ __forceinline__ void proc_entry(const float zv[16],
                                           const float e[16], float c2v,
                                           float z2, int idx, float& best,
                                           int& bi) {
#pragma clang fp contract(off)
  float m[16];
#pragma unroll
  for (int d = 0; d < 16; ++d) m[d] = zv[d] * e[d];
  float l0 = (m[0] + m[4]) + (m[8] + m[12]);
  float l1 = (m[1] + m[5]) + (m[9] + m[13]);
  float l2 = (m[2] + m[6]) + (m[10] + m[14]);
  float l3 = (m[3] + m[7]) + (m[11] + m[15]);
  const float dot = (l0 + l1) + (l2 + l3);
  const float d2 = (z2 - 2.0f * dot) + c2v;
  const bool lt = d2 < best;  // strict: ascending scan -> first-wins
  best = lt ? d2 : best;
  bi = lt ? idx : bi;
}

// v16 k_assign: v13's SMEM-stream structure with R=4 pixel blocking.
// 256 blocks x 1024 threads (16 waves); block = (c, chunk of 256 pixels).
// Each lane owns 4 pixels (zv[4][16] = 64 VGPR; entries stay in SGPRs so
// no VGPR entry staging -> the v2/v3 spill trigger is absent; no float4
// rotation). Wave w scans the disjoint ascending slice [w*64, w*64+64).
// Per lgkmcnt(0) drain, compute quadruples vs R=1 (~1000 cyc) -> drain
// count per wave halves vs v13 (32 vs 64) and SMEM traffic halves again.
__global__ __launch_bounds__(1024, 4) void k_assign(
    const float* __restrict__ z, const float* __restrict__ cb,
    float* __restrict__ out, float* __restrict__ ws_commit_arr) {
  __shared__ float s_c2[VOCAB];         // 4KB
  __shared__ float s_best[16 * 256];    // 16KB: per-wave cand per pixel
  __shared__ int s_bi[16 * 256];        // 16KB
  __shared__ float s_red[4];

  const int c = blockIdx.x >> 5;
  const int chunk = blockIdx.x & 31;    // chunk of 256 pixels
  const int t = threadIdx.x;
  const int pix = t & 63;
  const int w = t >> 6;
  // provably wave-uniform wave id -> scalar (SGPR) entry addressing below
  const int wu = __builtin_amdgcn_readfirstlane(w);

  const float* cbc = cb + (size_t)c * VOCAB * CDIM;

  // ||cb||^2 for all 1024 entries (np.sum(cb*cb,-1), pairwise 8-acc order)
  {
    float e[16];
#pragma unroll
    for (int d = 0; d < 16; ++d) e[d] = cbc[(size_t)t * CDIM + d];
    s_c2[t] = npsum16sq(e);
  }

  const int nbase = chunk * 256;    // first pixel id (256 | 1024 -> one b)
  const int b = nbase >> 10;        // batch
  const int hwb = nbase & 1023;     // base h*W + w

  // zv[r][d] = z[b, c*16+d, hwb + r*64 + pix]; 64-lane coalesced per (r,d)
  const float* zbase = z + ((size_t)(b * 128 + c * 16)) * HW + hwb + pix;
  float zv[4][16];
  float z2[4];
#pragma unroll
  for (int r = 0; r < 4; ++r) {
#pragma unroll
    for (int d = 0; d < 16; ++d) zv[r][d] = zbase[(size_t)d * HW + r * 64];
    z2[r] = npsum16sq(zv[r]);
  }

  __syncthreads();  // s_c2 ready

  // wave wu scans entries [wu*64, wu*64+64), ascending
  const int vbase = wu * 64;
  const float* ep = cbc + (size_t)vbase * CDIM;  // uniform (SGPR) pointer

  float best[4] = {INFINITY, INFINITY, INFINITY, INFINITY};
  int bi[4] = {0, 0, 0, 0};

#pragma unroll 2
  for (int k = 0; k < 64; k += 2) {
    // two entries per body (SGPR x16 loads); each feeds all 4 pixels
    float ea[16], eb[16];
#pragma unroll
    for (int d = 0; d < 16; ++d) ea[d] = ep[(size_t)k * CDIM + d];
#pragma unroll
    for (int d = 0; d < 16; ++d) eb[d] = ep[(size_t)(k + 1) * CDIM + d];
    const float cv0 = s_c2[vbase + k];
    const float cv1 = s_c2[vbase + k + 1];
#pragma unroll
    for (int r = 0; r < 4; ++r)
      proc_entry(zv[r], ea, cv0, z2[r], vbase + k, best[r], bi[r]);
#pragma unroll
    for (int r = 0; r < 4; ++r)
      proc_entry(zv[r], eb, cv1, z2[r], vbase + k + 1, best[r], bi[r]);
  }

#pragma unroll
  for (int r = 0; r < 4; ++r) {
    s_best[w * 256 + r * 64 + pix] = best[r];
    s_bi[w * 256 + r * 64 + pix] = bi[r];
  }
  __syncthreads();

  // threads 0..255 (waves 0-3): combine the 16 per-wave candidates for
  // pixel p_local = t. Wave slices are disjoint ascending ranges; break
  // float ties by lower index -> np.argmin first-wins exactly.
  if (t < 256) {
    const int r = t >> 6;  // this thread's own zv[r] IS pixel t's z
    float bb = s_best[t];
    int bbi = s_bi[t];
#pragma unroll
    for (int s = 1; s < 16; ++s) {
      const float ob = s_best[s * 256 + t];
      const int oi = s_bi[s * 256 + t];
      const bool take = (ob < bb) || (ob == bb && oi < bbi);
      bb = take ? ob : bb;
      bbi = take ? oi : bbi;
    }

    const int hw = hwb + t;  // pixel t's h*W+w (t = r*64 + pix)
    const float* qe = cbc + (size_t)bbi * CDIM;  // winning entry (L2-hot)
    float comm = 0.f;
#pragma unroll
    for (int d = 0; d < 16; ++d) {
      float zq = qe[d];
      float diff, qst;
      {
#pragma clang fp contract(off)
        diff = zv[r][d] - zq;
        qst = zv[r][d] + (zq - zv[r][d]);  // zq_st = zp + (zq - zp)
      }
      comm += diff * diff;
      out[OFF_QUANT + ((size_t)(b * 128 + c * 16 + d)) * HW + hw] = qst;
    }
    out[OFF_IDX + ((size_t)(b * NCB + c)) * HW + hw] = (float)bbi;

    // commitment partial: reduce waves 0-3 -> one plain store per block
#pragma unroll
    for (int off = 32; off; off >>= 1) comm += __shfl_down(comm, off);
    if ((t & 63) == 0) s_red[t >> 6] = comm;
  }
  __syncthreads();
  if (t == 0)
    ws_commit_arr[blockIdx.x] = (s_red[0] + s_red[1]) + (s_red[2] + s_red[3]);
}

// k_stats: exact v8/v13/v15 (proven fast). 256 blocks = (c, d, half) x
// 1024 threads; hoisted loads (one latency exposure), LDS-atomic binning,
// dense partial writes, zero global atomics, zero fences.
__global__ __launch_bounds__(1024, 4) void k_stats(
    const float* __restrict__ z, const float* __restrict__ outbuf,
    float* __restrict__ ws_counts_p, float* __restrict__ ws_sums_p) {
  __shared__ float s_sum[VOCAB];  // 4KB
  __shared__ float s_cnt[VOCAB];  // 4KB (d==0 blocks only)
  const int c = blockIdx.x >> 5;
  const int d = (blockIdx.x >> 1) & 15;
  const int half = blockIdx.x & 1;
  const int t = threadIdx.x;

  s_sum[t] = 0.f;
  if (d == 0) s_cnt[t] = 0.f;

  // hoist all loads: 4 idx + 4 z, independent -> one latency exposure
  int bidx[4];
  float zval[4];
#pragma unroll
  for (int k = 0; k < 4; ++k) {
    const int bb = half * 4 + k;  // batch
    bidx[k] = (int)outbuf[OFF_IDX + ((size_t)(bb * NCB + c)) * HW + t];
    zval[k] = z[((size_t)(bb * 128 + c * 16 + d)) * HW + t];
  }
  __syncthreads();  // zero-init visible

#pragma unroll
  for (int k = 0; k < 4; ++k) {
    atomicAdd(&s_sum[bidx[k]], zval[k]);  // ds_add_f32, banked
    if (d == 0) atomicAdd(&s_cnt[bidx[k]], 1.0f);
  }
  __syncthreads();

  ws_sums_p[((size_t)((c * CDIM + d) * 2 + half)) * VOCAB + t] = s_sum[t];
  if (d == 0) ws_counts_p[(c * 2 + half) * VOCAB + t] = s_cnt[t];
}

// k_update: exact v15 (256 blocks = 32 slices/c) with the commitment
// reduce adjusted to 256 partials.
__global__ __launch_bounds__(256) void k_update(
    const float* __restrict__ ema_count, const float* __restrict__ ema_weight,
    const float* __restrict__ ws_counts_p, const float* __restrict__ ws_sums_p,
    const float* __restrict__ ws_commit_arr, float* __restrict__ out) {
  const int c = blockIdx.x >> 5;
  const int part = blockIdx.x & 31;   // 32 slices per codebook
  const int t = threadIdx.x;
  __shared__ float s_red[4];
  __shared__ float s_n;
  __shared__ double s_dred[4];

  const float* cp0 = ws_counts_p + (c * 2 + 0) * VOCAB;
  const float* cp1 = ws_counts_p + (c * 2 + 1) * VOCAB;

  float psum = 0.f;
#pragma unroll
  for (int k = 0; k < 4; ++k) {
    const int v = k * 256 + t;
    psum += 0.99f * ema_count[c * VOCAB + v] + 0.01f * (cp0[v] + cp1[v]);
  }
#pragma unroll
  for (int off = 32; off; off >>= 1) psum += __shfl_down(psum, off);
  if ((t & 63) == 0) s_red[t >> 6] = psum;
  __syncthreads();
  if (t == 0) s_n = (s_red[0] + s_red[1]) + (s_red[2] + s_red[3]);
  __syncthreads();
  const float nsum = s_n;
  const float veps = 0.01024f;  // VOCAB * 1e-5

  // new_count: 32 entries per block
  if (t < 32) {
    const int v = part * 32 + t;
    out[OFF_NCNT + c * VOCAB + v] =
        0.99f * ema_count[c * VOCAB + v] + 0.01f * (cp0[v] + cp1[v]);
  }

  // new_weight / new_codebooks: 512 elements per block, coalesced stores
#pragma unroll
  for (int k = 0; k < 2; ++k) {
    const int i = part * 512 + k * 256 + t;  // element within codebook c
    const int v = i >> 4;
    const int d = i & 15;
    const float nc =
        0.99f * ema_count[c * VOCAB + v] + 0.01f * (cp0[v] + cp1[v]);
    const float cnt = (nc + 1e-5f) / (nsum + veps) * nsum;
    const size_t gi = (size_t)c * VOCAB * CDIM + i;
    const float s0 = ws_sums_p[((size_t)((c * CDIM + d) * 2 + 0)) * VOCAB + v];
    const float s1 = ws_sums_p[((size_t)((c * CDIM + d) * 2 + 1)) * VOCAB + v];
    const float nw = 0.99f * ema_weight[gi] + 0.01f * (s0 + s1);
    out[OFF_NWT + gi] = nw;
    out[OFF_NCB + gi] = nw / cnt;
  }

  if (blockIdx.x == 0) {
    double ps = (double)ws_commit_arr[t];
#pragma unroll
    for (int off = 32; off; off >>= 1) ps += __shfl_down(ps, off);
    if ((t & 63) == 0) s_dred[t >> 6] = ps;
    __syncthreads();
    if (t == 0)
      out[OFF_COMMIT] =
          (float)(((s_dred[0] + s_dred[1]) + (s_dred[2] + s_dred[3])) /
                  1048576.0);
  }
}

extern "C" void kernel_launch(void* const* d_in, const int* in_sizes, int n_in,
                              void* d_out, int out_size, void* d_ws,
                              size_t ws_size, hipStream_t stream) {
  const float* z = (const float*)d_in[0];
  const float* codebooks = (const float*)d_in[1];
  const float* ema_count = (const float*)d_in[2];
  const float* ema_weight = (const float*)d_in[3];
  float* out = (float*)d_out;

  float* wsf = (float*)d_ws;
  float* ws_counts_p = wsf + WS_CNTP_OFF;
  float* ws_sums_p = wsf + WS_SUMP_OFF;
  float* ws_commit_arr = wsf + WS_CARR_OFF;

  // no memset: all workspace words are written before being read

  k_assign<<<dim3(256), dim3(1024), 0, stream>>>(z, codebooks, out,
                                                 ws_commit_arr);
  k_stats<<<dim3(256), dim3(1024), 0, stream>>>(z, out, ws_counts_p,
                                                ws_sums_p);
  k_update<<<dim3(256), dim3(256), 0, stream>>>(ema_count, ema_weight,
                                                ws_counts_p, ws_sums_p,
                                                ws_commit_arr, out);
}

// Round 16
// 129.757 us; speedup vs baseline: 1.0824x; 1.0824x over previous
//
#include <hip/hip_runtime.h>

// SimVQuantizer: B=8, D=128 (N_CB=8 x CDIM=16), H=W=32 -> 8192 pixels.
// FINAL (v15 = session best, 130.3us): k_assign v13 (R=2 SGPR-stream,
// 62us) + k_stats v8 + k_update widened. v16's R=4 spilled (VGPR=64,
// WRITE 69.9MB scratch) and is reverted.
// Outputs (FLOAT32, concatenated flat):
//   quantized  [8,128,32,32]  = 1048576   @ 0
//   indices    [8,8,32,32]    =   65536   @ 1048576
//   commitment scalar         =       1   @ 1114112
//   new_codebooks [8,1024,16] =  131072   @ 1114113
//   new_count  [8,1024]       =    8192   @ 1245185
//   new_weight [8,1024,16]    =  131072   @ 1253377

#define NCB   8
#define VOCAB 1024
#define CDIM  16
#define NPIX  8192   // B*H*W
#define HW    1024   // H*W

#define OFF_QUANT  0
#define OFF_IDX    1048576
#define OFF_COMMIT 1114112
#define OFF_NCB    1114113
#define OFF_NCNT   1245185
#define OFF_NWT    1253377

// workspace layout (floats):
//   counts_p [8][2][1024]      @ 0       (per-(c,half) partial counts)
//   sums_p   [8][16][2][1024]  @ 16384   (per-(c,d,half) partial sums)
//   commit_arr [512]           @ 278528  (per-assign-block partials)
// No memset: every word is written before it is read.
// Lessons pinned: no global atomics in hot paths (v6: 1.1M atomics = 34MB
// TCC-RMW write amplification, invariant ~150us floor); no per-block
// __threadfence finisher patterns (v10: per-XCD L2 writebacks ~100x a
// kernel boundary); SMEM s_loads can't be counted-pipelined (out-of-order
// -> lgkmcnt(0) only); packed-f32 never reduces issue count on hipcc
// (v9, v12); 3-kernel split is structurally optimal (fusions v7/v10/v14
// all regressed); R-blocking: R=2 safe with SGPR entries (VGPR=40),
// R=4 spills regardless (v2/v3/v16).
#define WS_CNTP_OFF 0
#define WS_SUMP_OFF (NCB * 2 * VOCAB)
#define WS_CARR_OFF (NCB * 2 * VOCAB + NCB * CDIM * 2 * VOCAB)

// numpy pairwise_sum (order-preserving 8-accumulator) for n=16:
// r[j] = a[j] + a[j+8];  res = ((r0+r1)+(r2+r3)) + ((r4+r5)+(r6+r7))
__device__ __forceinline__ float npsum16(const float m[16]) {
#pragma clang fp contract(off)
  float r0 = m[0] + m[8];
  float r1 = m[1] + m[9];
  float r2 = m[2] + m[10];
  float r3 = m[3] + m[11];
  float r4 = m[4] + m[12];
  float r5 = m[5] + m[13];
  float r6 = m[6] + m[14];
  float r7 = m[7] + m[15];
  return ((r0 + r1) + (r2 + r3)) + ((r4 + r5) + (r6 + r7));
}

__device__ __forceinline__ float npsum16sq(const float a[16]) {
#pragma clang fp contract(off)
  float m[16];
#pragma unroll
  for (int d = 0; d < 16; ++d) m[d] = a[d] * a[d];
  return npsum16(m);
}

// One entry's distance + argmin step. numpy einsum (optimize=False) npyv
// contig order for n=16, then (z2 - 2*dot) + c2 — bit-identical to v1.
__device__ __forceinline__ void proc_entry(const float zv[16],
                                           const float e[16], float c2v,
                                           float z2, int idx, float& best,
                                           int& bi) {
#pragma clang fp contract(off)
  float m[16];
#pragma unroll
  for (int d = 0; d < 16; ++d) m[d] = zv[d] * e[d];
  float l0 = (m[0] + m[4]) + (m[8] + m[12]);
  float l1 = (m[1] + m[5]) + (m[9] + m[13]);
  float l2 = (m[2] + m[6]) + (m[10] + m[14]);
  float l3 = (m[3] + m[7]) + (m[11] + m[15]);
  const float dot = (l0 + l1) + (l2 + l3);
  const float d2 = (z2 - 2.0f * dot) + c2v;
  const bool lt = d2 < best;  // strict: ascending scan -> first-wins
  best = lt ? d2 : best;
  bi = lt ? idx : bi;
}

// k_assign: exact v13 (62us measured — best of 6 structural variants;
// at practical floor under exact-numpy-argmin constraints: ~30us VALU
// floor + un-pipelineable SMEM drain latency).
// 512 blocks x 512 threads; R=2 pixels/lane; SMEM-streamed entries.
__global__ __launch_bounds__(512, 4) void k_assign(
    const float* __restrict__ z, const float* __restrict__ cb,
    float* __restrict__ out, float* __restrict__ ws_commit_arr) {
  __shared__ float s_c2[VOCAB];         // 4KB
  __shared__ float s_best[8 * 128];     // 4KB: per-wave cand per pixel
  __shared__ int s_bi[8 * 128];         // 4KB
  __shared__ float s_red[2];

  const int c = blockIdx.x >> 6;
  const int pchunk = blockIdx.x & 63;   // chunk of 128 pixels
  const int t = threadIdx.x;
  const int pix = t & 63;
  const int w = t >> 6;
  // provably wave-uniform wave id -> scalar (SGPR) entry addressing below
  const int wu = __builtin_amdgcn_readfirstlane(w);

  const float* cbc = cb + (size_t)c * VOCAB * CDIM;

  // ||cb||^2 for all 1024 entries (np.sum(cb*cb,-1), pairwise 8-acc order)
  for (int v = t; v < VOCAB; v += 512) {
    float e[16];
#pragma unroll
    for (int d = 0; d < 16; ++d) e[d] = cbc[(size_t)v * CDIM + d];
    s_c2[v] = npsum16sq(e);
  }

  const int nbase = pchunk * 128;   // first pixel id (128 | 1024 -> one b)
  const int b = nbase >> 10;        // batch
  const int hwb = nbase & 1023;     // base h*W + w

  // zv[r][d] = z[b, c*16+d, hwb + r*64 + pix]; 64-lane coalesced per (r,d)
  const float* zbase = z + ((size_t)(b * 128 + c * 16)) * HW + hwb + pix;
  float zv[2][16];
  float z2[2];
#pragma unroll
  for (int r = 0; r < 2; ++r) {
#pragma unroll
    for (int d = 0; d < 16; ++d) zv[r][d] = zbase[(size_t)d * HW + r * 64];
    z2[r] = npsum16sq(zv[r]);
  }

  __syncthreads();  // s_c2 ready

  // wave wu scans entries [wu*128, wu*128+128), ascending
  const int vbase = wu * 128;
  const float* ep = cbc + (size_t)vbase * CDIM;  // uniform (SGPR) pointer

  float best[2] = {INFINITY, INFINITY};
  int bi[2] = {0, 0};

#pragma unroll 2
  for (int k = 0; k < 128; k += 2) {
    // two entries per body (SGPR x16 loads); each feeds both pixels
    float ea[16], eb[16];
#pragma unroll
    for (int d = 0; d < 16; ++d) ea[d] = ep[(size_t)k * CDIM + d];
#pragma unroll
    for (int d = 0; d < 16; ++d) eb[d] = ep[(size_t)(k + 1) * CDIM + d];
    const float cv0 = s_c2[vbase + k];
    const float cv1 = s_c2[vbase + k + 1];
    proc_entry(zv[0], ea, cv0, z2[0], vbase + k, best[0], bi[0]);
    proc_entry(zv[1], ea, cv0, z2[1], vbase + k, best[1], bi[1]);
    proc_entry(zv[0], eb, cv1, z2[0], vbase + k + 1, best[0], bi[0]);
    proc_entry(zv[1], eb, cv1, z2[1], vbase + k + 1, best[1], bi[1]);
  }

#pragma unroll
  for (int r = 0; r < 2; ++r) {
    s_best[w * 128 + r * 64 + pix] = best[r];
    s_bi[w * 128 + r * 64 + pix] = bi[r];
  }
  __syncthreads();

  // threads 0..127 (waves 0,1): combine the 8 per-wave candidates for
  // pixel p_local = t. Wave slices are disjoint ascending ranges; break
  // float ties by lower index -> np.argmin first-wins exactly.
  if (t < 128) {
    const int r = t >> 6;  // this thread's own zv[r] IS pixel t's z
    float bb = s_best[t];
    int bbi = s_bi[t];
#pragma unroll
    for (int s = 1; s < 8; ++s) {
      const float ob = s_best[s * 128 + t];
      const int oi = s_bi[s * 128 + t];
      const bool take = (ob < bb) || (ob == bb && oi < bbi);
      bb = take ? ob : bb;
      bbi = take ? oi : bbi;
    }

    const int hw = hwb + t;  // pixel t's h*W+w (t = r*64 + pix)
    const float* qe = cbc + (size_t)bbi * CDIM;  // winning entry (L2-hot)
    float comm = 0.f;
#pragma unroll
    for (int d = 0; d < 16; ++d) {
      float zq = qe[d];
      float diff, qst;
      {
#pragma clang fp contract(off)
        diff = zv[r][d] - zq;
        qst = zv[r][d] + (zq - zv[r][d]);  // zq_st = zp + (zq - zp)
      }
      comm += diff * diff;
      out[OFF_QUANT + ((size_t)(b * 128 + c * 16 + d)) * HW + hw] = qst;
    }
    out[OFF_IDX + ((size_t)(b * NCB + c)) * HW + hw] = (float)bbi;

    // commitment partial: reduce waves 0,1 -> one plain store per block
#pragma unroll
    for (int off = 32; off; off >>= 1) comm += __shfl_down(comm, off);
    if ((t & 63) == 0) s_red[t >> 6] = comm;
  }
  __syncthreads();
  if (t == 0) ws_commit_arr[blockIdx.x] = s_red[0] + s_red[1];
}

// k_stats: exact v8 (proven fast). 256 blocks = (c, d, half) x 1024
// threads; hoisted loads (one latency exposure), LDS-atomic binning,
// dense partial writes, zero global atomics, zero fences.
__global__ __launch_bounds__(1024, 4) void k_stats(
    const float* __restrict__ z, const float* __restrict__ outbuf,
    float* __restrict__ ws_counts_p, float* __restrict__ ws_sums_p) {
  __shared__ float s_sum[VOCAB];  // 4KB
  __shared__ float s_cnt[VOCAB];  // 4KB (d==0 blocks only)
  const int c = blockIdx.x >> 5;
  const int d = (blockIdx.x >> 1) & 15;
  const int half = blockIdx.x & 1;
  const int t = threadIdx.x;

  s_sum[t] = 0.f;
  if (d == 0) s_cnt[t] = 0.f;

  // hoist all loads: 4 idx + 4 z, independent -> one latency exposure
  int bidx[4];
  float zval[4];
#pragma unroll
  for (int k = 0; k < 4; ++k) {
    const int bb = half * 4 + k;  // batch
    bidx[k] = (int)outbuf[OFF_IDX + ((size_t)(bb * NCB + c)) * HW + t];
    zval[k] = z[((size_t)(bb * 128 + c * 16 + d)) * HW + t];
  }
  __syncthreads();  // zero-init visible

#pragma unroll
  for (int k = 0; k < 4; ++k) {
    atomicAdd(&s_sum[bidx[k]], zval[k]);  // ds_add_f32, banked
    if (d == 0) atomicAdd(&s_cnt[bidx[k]], 1.0f);
  }
  __syncthreads();

  ws_sums_p[((size_t)((c * CDIM + d) * 2 + half)) * VOCAB + t] = s_sum[t];
  if (d == 0) ws_counts_p[(c * 2 + half) * VOCAB + t] = s_cnt[t];
}

// k_update: widened (256 blocks = 32 slices/c) x 256 threads. The nsum
// block (identical 256-thread tree -> bit-identical nsum) is replicated;
// each block writes a small coalesced output slice.
__global__ __launch_bounds__(256) void k_update(
    const float* __restrict__ ema_count, const float* __restrict__ ema_weight,
    const float* __restrict__ ws_counts_p, const float* __restrict__ ws_sums_p,
    const float* __restrict__ ws_commit_arr, float* __restrict__ out) {
  const int c = blockIdx.x >> 5;
  const int part = blockIdx.x & 31;   // 32 slices per codebook
  const int t = threadIdx.x;
  __shared__ float s_red[4];
  __shared__ float s_n;
  __shared__ double s_dred[4];

  const float* cp0 = ws_counts_p + (c * 2 + 0) * VOCAB;
  const float* cp1 = ws_counts_p + (c * 2 + 1) * VOCAB;

  float psum = 0.f;
#pragma unroll
  for (int k = 0; k < 4; ++k) {
    const int v = k * 256 + t;
    psum += 0.99f * ema_count[c * VOCAB + v] + 0.01f * (cp0[v] + cp1[v]);
  }
#pragma unroll
  for (int off = 32; off; off >>= 1) psum += __shfl_down(psum, off);
  if ((t & 63) == 0) s_red[t >> 6] = psum;
  __syncthreads();
  if (t == 0) s_n = (s_red[0] + s_red[1]) + (s_red[2] + s_red[3]);
  __syncthreads();
  const float nsum = s_n;
  const float veps = 0.01024f;  // VOCAB * 1e-5

  // new_count: 32 entries per block
  if (t < 32) {
    const int v = part * 32 + t;
    out[OFF_NCNT + c * VOCAB + v] =
        0.99f * ema_count[c * VOCAB + v] + 0.01f * (cp0[v] + cp1[v]);
  }

  // new_weight / new_codebooks: 512 elements per block, coalesced stores
#pragma unroll
  for (int k = 0; k < 2; ++k) {
    const int i = part * 512 + k * 256 + t;  // element within codebook c
    const int v = i >> 4;
    const int d = i & 15;
    const float nc =
        0.99f * ema_count[c * VOCAB + v] + 0.01f * (cp0[v] + cp1[v]);
    const float cnt = (nc + 1e-5f) / (nsum + veps) * nsum;
    const size_t gi = (size_t)c * VOCAB * CDIM + i;
    const float s0 = ws_sums_p[((size_t)((c * CDIM + d) * 2 + 0)) * VOCAB + v];
    const float s1 = ws_sums_p[((size_t)((c * CDIM + d) * 2 + 1)) * VOCAB + v];
    const float nw = 0.99f * ema_weight[gi] + 0.01f * (s0 + s1);
    out[OFF_NWT + gi] = nw;
    out[OFF_NCB + gi] = nw / cnt;
  }

  if (blockIdx.x == 0) {
    double ps = 0.0;
#pragma unroll
    for (int k = 0; k < 2; ++k) ps += (double)ws_commit_arr[k * 256 + t];
#pragma unroll
    for (int off = 32; off; off >>= 1) ps += __shfl_down(ps, off);
    if ((t & 63) == 0) s_dred[t >> 6] = ps;
    __syncthreads();
    if (t == 0)
      out[OFF_COMMIT] =
          (float)(((s_dred[0] + s_dred[1]) + (s_dred[2] + s_dred[3])) /
                  1048576.0);
  }
}

extern "C" void kernel_launch(void* const* d_in, const int* in_sizes, int n_in,
                              void* d_out, int out_size, void* d_ws,
                              size_t ws_size, hipStream_t stream) {
  const float* z = (const float*)d_in[0];
  const float* codebooks = (const float*)d_in[1];
  const float* ema_count = (const float*)d_in[2];
  const float* ema_weight = (const float*)d_in[3];
  float* out = (float*)d_out;

  float* wsf = (float*)d_ws;
  float* ws_counts_p = wsf + WS_CNTP_OFF;
  float* ws_sums_p = wsf + WS_SUMP_OFF;
  float* ws_commit_arr = wsf + WS_CARR_OFF;

  // no memset: all workspace words are written before being read

  k_assign<<<dim3(512), dim3(512), 0, stream>>>(z, codebooks, out,
                                                ws_commit_arr);
  k_stats<<<dim3(256), dim3(1024), 0, stream>>>(z, out, ws_counts_p,
                                                ws_sums_p);
  k_update<<<dim3(256), dim3(256), 0, stream>>>(ema_count, ema_weight,
                                                ws_counts_p, ws_sums_p,
                                                ws_commit_arr, out);
}